// Round 11
// baseline (417.410 us; speedup 1.0000x reference)
//
#include <hip/hip_runtime.h>
#include <math.h>

#define N_ANCH 134400
#define N_CLS  80
#define TOPK   4096
#define MAX_OUT 300
#define TIECAP 16384

// ---- ws layout (bytes) ----
#define SARR_OFF   0u          // u32[134400] = 537600
#define GHIST_OFF  537600u     // u32[4][256] = 4096
#define STATE_OFF  541696u     // u32 pref(S* prefix), u32 rank
#define CNT_OFF    541704u     // u32 gather counter
#define TIECNT_OFF 541708u     // u32
#define ISTAR_OFF  541712u     // u32
#define TIEBUF_OFF 541728u     // u32[16384] = 65536
#define CANDK_OFF  607264u     // u64[4096] = 32768
#define CBOX_OFF   640032u     // float4[4096] = 65536 (16B aligned)
#define CSCORE_OFF 705568u     // f32[4096]
#define CCLS_OFF   721952u     // i32[4096]
#define SUP_OFF    738336u     // u64[4096*64] = 2097152
#define WS_NEEDED  2835488u
#define MEMSET_OFF 537600u
#define MEMSET_LEN 4112u       // ghist + state + counter + tiecnt

static __device__ __forceinline__ unsigned int ord_f32(float f) {
  unsigned int u = __float_as_uint(f);
  return (u & 0x80000000u) ? ~u : (u | 0x80000000u);
}
static __device__ __forceinline__ float unord_f32(unsigned int o) {
  unsigned int u = (o & 0x80000000u) ? (o ^ 0x80000000u) : ~o;
  return __uint_as_float(u);
}

// K1: per-anchor max class score -> 32-bit order-preserving key
__global__ void k_keys(const float* __restrict__ p, unsigned int* __restrict__ sarr) {
  int i = blockIdx.x * blockDim.x + threadIdx.x;
  if (i >= N_ANCH) return;
  float best = p[4 * N_ANCH + i];
#pragma unroll 4
  for (int c = 1; c < N_CLS; ++c) {
    float v = p[(4 + c) * N_ANCH + i];
    best = fmaxf(best, v);
  }
  float m = (best >= 0.25f) ? best : -INFINITY;
  sarr[i] = ord_f32(m);
}

// Grid-wide 8-bit MSB radix histogram, pass PASS (shift 24-8*PASS).
template <int PASS>
__global__ __launch_bounds__(256) void k_hist(const unsigned int* __restrict__ sarr,
                                              const unsigned int* __restrict__ state,
                                              unsigned int* __restrict__ ghist) {
  __shared__ unsigned int h[256];
  int tid = threadIdx.x;
  h[tid] = 0u;
  __syncthreads();
  int i = blockIdx.x * 256 + tid;   // grid == N_ANCH exactly (525*256)
  unsigned int s = sarr[i];
  if (PASS == 0) {
    atomicAdd(&h[s >> 24], 1u);
  } else {
    const int sh = 24 - 8 * PASS;   // 16, 8, 0
    if ((s >> (sh + 8)) == state[0])
      atomicAdd(&h[(s >> sh) & 255u], 1u);
  }
  __syncthreads();
  if (h[tid]) atomicAdd(&ghist[PASS * 256 + tid], h[tid]);
}

// Scan 256 bins from top, descend one radix level. state = {pref, rank}.
template <int PASS>
__global__ __launch_bounds__(256) void k_scan(const unsigned int* __restrict__ ghist,
                                              unsigned int* __restrict__ state) {
  __shared__ unsigned int h[256];
  int tid = threadIdx.x;
  h[tid] = ghist[PASS * 256 + tid];
  __syncthreads();
  if (tid == 0) {
    unsigned int r    = (PASS == 0) ? (unsigned)TOPK : state[1];
    unsigned int pref = (PASS == 0) ? 0u : state[0];
    unsigned int cum = 0u;
    for (int b = 255; b >= 0; --b) {
      unsigned int c = h[b];
      if (cum + c >= r) { state[0] = (pref << 8) | (unsigned int)b; state[1] = r - cum; break; }
      cum += c;
    }
  }
}

// Collect indices whose score-key equals S* (exact ties at the cut)
__global__ void k_tiecollect(const unsigned int* __restrict__ sarr,
                             const unsigned int* __restrict__ state,
                             unsigned int* __restrict__ tiecnt,
                             unsigned int* __restrict__ tiebuf) {
  int i = blockIdx.x * 256 + threadIdx.x;
  if (sarr[i] == state[0]) {
    unsigned int pos = atomicAdd(tiecnt, 1u);
    if (pos < TIECAP) tiebuf[pos] = (unsigned int)i;
  }
}

// I* = rank-th smallest index among ties (rank = state[1], 1-based).
__global__ __launch_bounds__(256) void k_tiesel(const unsigned int* __restrict__ state,
                                                const unsigned int* __restrict__ tiecnt,
                                                const unsigned int* __restrict__ tiebuf,
                                                unsigned int* __restrict__ Istar) {
  __shared__ unsigned int buf[TIECAP];  // exactly 64KB static LDS
  unsigned int n = *tiecnt; if (n > TIECAP) n = TIECAP;
  unsigned int rf = state[1];
  for (unsigned int t = threadIdx.x; t < n; t += 256) buf[t] = tiebuf[t];
  __syncthreads();
  for (unsigned int t = threadIdx.x; t < n; t += 256) {
    unsigned int v = buf[t], r = 0u;
    for (unsigned int j = 0; j < n; ++j) r += (buf[j] < v) ? 1u : 0u;
    if (r == rf - 1u) *Istar = v;
  }
}

// K3: gather exactly-4096 selected anchors into 64-bit keys (score desc, idx asc)
__global__ void k_gather(const unsigned int* __restrict__ sarr,
                         const unsigned int* __restrict__ state,
                         const unsigned int* __restrict__ Istar,
                         unsigned int* __restrict__ counter,
                         unsigned long long* __restrict__ candk) {
  int i = blockIdx.x * 256 + threadIdx.x;
  unsigned int s = sarr[i];
  unsigned int S = state[0];
  bool take = (s > S) || (s == S && (unsigned int)i <= *Istar);
  if (take) {
    unsigned int pos = atomicAdd(counter, 1u);
    if (pos < TOPK)
      candk[pos] = ((unsigned long long)s << 32) |
                   (unsigned long long)(~(unsigned int)i);
  }
}

// K4: bitonic sort 4096 keys descending in LDS (exact JAX candidate order)
__global__ __launch_bounds__(1024) void k_sort(unsigned long long* __restrict__ candk) {
  __shared__ unsigned long long s[TOPK];
  for (int i = threadIdx.x; i < TOPK; i += 1024) s[i] = candk[i];
  __syncthreads();
  for (int k = 2; k <= TOPK; k <<= 1) {
    for (int j = k >> 1; j > 0; j >>= 1) {
      for (int i = threadIdx.x; i < TOPK; i += 1024) {
        int ixj = i ^ j;
        if (ixj > i) {
          bool up = ((i & k) == 0);
          unsigned long long a = s[i], b = s[ixj];
          bool sw = up ? (a < b) : (a > b);  // descending overall
          if (sw) { s[i] = b; s[ixj] = a; }
        }
      }
      __syncthreads();
    }
  }
  for (int i = threadIdx.x; i < TOPK; i += 1024) candk[i] = s[i];
}

// K5: decode per-candidate box / class / score
__global__ void k_fill(const float* __restrict__ p,
                       const unsigned long long* __restrict__ candk,
                       float4* __restrict__ cbox,
                       float* __restrict__ cscore,
                       int* __restrict__ ccls) {
  int c = blockIdx.x * blockDim.x + threadIdx.x;
  if (c >= TOPK) return;
  unsigned long long k = candk[c];
  float score = unord_f32((unsigned int)(k >> 32));
  int idx = (int)(~(unsigned int)(k & 0xFFFFFFFFull));
  float xc = p[idx];
  float yc = p[N_ANCH + idx];
  float w  = p[2 * N_ANCH + idx];
  float h  = p[3 * N_ANCH + idx];
  float hw = floorf(w * 0.5f), hh = floorf(h * 0.5f);
  cbox[c] = make_float4(xc - hw, yc - hh, xc + hw, yc + hh);
  float best = p[4 * N_ANCH + idx];
  int cls = 0;
  for (int cc = 1; cc < N_CLS; ++cc) {
    float v = p[(4 + cc) * N_ANCH + idx];
    if (v > best) { best = v; cls = cc; }
  }
  cscore[c] = score;
  ccls[c]   = cls;
}

// K6: suppression bitmask matrix (op-for-op reference IoU, j>i baked in)
__global__ void k_iou(const float4* __restrict__ cbox, unsigned long long* __restrict__ sup) {
  int g = blockIdx.x * blockDim.x + threadIdx.x;  // 4096*64 threads
  int row = g >> 6, word = g & 63;
  float4 bi = cbox[row];
  float ai = (bi.z - bi.x) * (bi.w - bi.y);
  unsigned long long m = 0ull;
  int j0 = word << 6;
  if (j0 + 63 > row) {
    for (int b = 0; b < 64; ++b) {
      int j = j0 + b;
      if (j <= row) continue;
      float4 bj = cbox[j];
      float aj = (bj.z - bj.x) * (bj.w - bj.y);
      float ltx = fmaxf(bi.x, bj.x), lty = fmaxf(bi.y, bj.y);
      float rbx = fminf(bi.z, bj.z), rby = fminf(bi.w, bj.w);
      float ww = fmaxf(rbx - ltx, 0.0f), hh = fmaxf(rby - lty, 0.0f);
      float inter = ww * hh;
      float uni = ai + aj - inter;
      float iou = inter / (uni + 1e-9f);
      if (iou > 0.5f) m |= (1ull << b);
    }
  }
  sup[g] = m;
}

// K7: greedy NMS, Phase A/B decomposition, early exit at 300th kept row.
// Phase A (serial, registers only): intra-chunk survivors via the 64x64
// diagonal block (lane l holds row l's word `chunk`); per-kept-row chain is
// ctz+shfl+AND — no LDS/global access on the critical path.
// Phase B (parallel): kept rows' full 512B masks applied to kw via
// independent coalesced global reads (pipelined, latency hidden).
// Legal early exit: output = first 300 kept candidates in score order; rows
// after the 300th kept are unobservable, so we stop mid-chunk and skip B.
__global__ __launch_bounds__(256) void k_nms_out(const float4* __restrict__ cbox,
                                                 const float* __restrict__ cscore,
                                                 const int* __restrict__ ccls,
                                                 const unsigned long long* __restrict__ sup,
                                                 float* __restrict__ out) {
  __shared__ unsigned long long skeep[64];
  __shared__ int s_list[MAX_OUT];
  __shared__ float s_fs[MAX_OUT];
  __shared__ int s_K;
  __shared__ int s_cnt;
  int tid = threadIdx.x;
  int lane = tid & 63, wave = tid >> 6;

  // ballot init: word (r*4 + wave) = ballot over coalesced cscore reads
  for (int r = 0; r < 16; ++r) {
    float sc = cscore[r * 256 + tid];
    unsigned long long m = __ballot(sc >= 0.25f);  // isfinite(masked) == passed threshold
    if (lane == 0) skeep[r * 4 + wave] = m;
  }
  if (tid == 0) { s_K = 0; s_cnt = 0; }
  __syncthreads();

  if (wave == 0) {
    unsigned long long kw = skeep[lane];  // lane owns keep-word `lane`
    int n = 0;
    for (int chunk = 0; chunk < 64 && n < MAX_OUT; ++chunk) {
      unsigned long long cur = __shfl(kw, chunk);  // alive rows in this chunk
      if (!cur) continue;
      // diagonal 64x64 block: lane l = row (chunk*64+l), word `chunk`
      unsigned long long diag = sup[(chunk * 64 + lane) * 64 + chunk];
      unsigned long long keptl = 0ull;
      while (cur) {
        int b = __builtin_ctzll(cur);        // row chunk*64+b is KEPT (final)
        if (lane == 0) s_list[n] = chunk * 64 + b;
        n++;
        keptl |= (1ull << b);
        if (n == MAX_OUT) break;
        unsigned long long mb = __shfl(diag, b);  // only j>b bits set
        cur &= ~mb;
        cur = (b == 63) ? 0ull : (cur & (~0ull << (b + 1)));
      }
      if (n == MAX_OUT) break;  // later rows unobservable; skip Phase B
      // Phase B: independent coalesced reads, pipelined
      while (keptl) {
        int b = __builtin_ctzll(keptl);
        keptl &= keptl - 1ull;
        kw &= ~sup[(chunk * 64 + b) * 64 + lane];  // row bit b survives (j>i only)
      }
    }
    if (lane == 0) s_K = n;
  }
  __syncthreads();

  int K = s_K;
  for (int r = tid; r < MAX_OUT; r += 256)
    s_fs[r] = (r < K) ? cscore[s_list[r]] : 0.0f;
  __syncthreads();

  float slast = s_fs[MAX_OUT - 1], sprev = s_fs[MAX_OUT - 2];
  bool tie = fabsf(slast - sprev) < 1e-6f;
  int local = 0;
  for (int r = tid; r < MAX_OUT; r += 256) {
    float fs = s_fs[r];
    float factor = tie ? ((fs - slast > 1e-5f) ? 1.0f : 0.0f) : 1.0f;
    float so = fs * factor;
    out[4 * MAX_OUT + r] = so;          // scores at [1200, 1500)
    if (so > 1e-5f) local++;
    if (r < K) {
      int c = s_list[r];
      float4 b = cbox[c];
      out[4 * r + 0] = b.x / 640.0f;    // boxes at [0, 1200)
      out[4 * r + 1] = b.y / 640.0f;
      out[4 * r + 2] = b.z / 640.0f;
      out[4 * r + 3] = b.w / 640.0f;
      out[5 * MAX_OUT + r] = (float)ccls[c];  // classes at [1500, 1800)
    } else {
      out[4 * r + 0] = 0.0f; out[4 * r + 1] = 0.0f;
      out[4 * r + 2] = 0.0f; out[4 * r + 3] = 0.0f;
      out[5 * MAX_OUT + r] = 0.0f;
    }
  }
  if (local) atomicAdd(&s_cnt, local);
  __syncthreads();
  if (tid == 0) out[6 * MAX_OUT] = (float)s_cnt;  // count at 1800
}

extern "C" void kernel_launch(void* const* d_in, const int* in_sizes, int n_in,
                              void* d_out, int out_size, void* d_ws, size_t ws_size,
                              hipStream_t stream) {
  const float* p = (const float*)d_in[0];
  float* out = (float*)d_out;
  char* ws = (char*)d_ws;

  if (ws_size < (size_t)WS_NEEDED) return;

  unsigned int* sarr   = (unsigned int*)(ws + SARR_OFF);
  unsigned int* ghist  = (unsigned int*)(ws + GHIST_OFF);
  unsigned int* state  = (unsigned int*)(ws + STATE_OFF);
  unsigned int* counter= (unsigned int*)(ws + CNT_OFF);
  unsigned int* tiecnt = (unsigned int*)(ws + TIECNT_OFF);
  unsigned int* Istar  = (unsigned int*)(ws + ISTAR_OFF);
  unsigned int* tiebuf = (unsigned int*)(ws + TIEBUF_OFF);
  unsigned long long* candk = (unsigned long long*)(ws + CANDK_OFF);
  float4* cbox              = (float4*)(ws + CBOX_OFF);
  float* cscore             = (float*)(ws + CSCORE_OFF);
  int* ccls                 = (int*)(ws + CCLS_OFF);
  unsigned long long* sup   = (unsigned long long*)(ws + SUP_OFF);

  const int NB = N_ANCH / 256;  // 525, exact

  hipMemsetAsync(ws + MEMSET_OFF, 0, MEMSET_LEN, stream);
  k_keys<<<NB, 256, 0, stream>>>(p, sarr);
  k_hist<0><<<NB, 256, 0, stream>>>(sarr, state, ghist);
  k_scan<0><<<1, 256, 0, stream>>>(ghist, state);
  k_hist<1><<<NB, 256, 0, stream>>>(sarr, state, ghist);
  k_scan<1><<<1, 256, 0, stream>>>(ghist, state);
  k_hist<2><<<NB, 256, 0, stream>>>(sarr, state, ghist);
  k_scan<2><<<1, 256, 0, stream>>>(ghist, state);
  k_hist<3><<<NB, 256, 0, stream>>>(sarr, state, ghist);
  k_scan<3><<<1, 256, 0, stream>>>(ghist, state);
  k_tiecollect<<<NB, 256, 0, stream>>>(sarr, state, tiecnt, tiebuf);
  k_tiesel<<<1, 256, 0, stream>>>(state, tiecnt, tiebuf, Istar);
  k_gather<<<NB, 256, 0, stream>>>(sarr, state, Istar, counter, candk);
  k_sort<<<1, 1024, 0, stream>>>(candk);
  k_fill<<<TOPK / 256, 256, 0, stream>>>(p, candk, cbox, cscore, ccls);
  k_iou<<<(TOPK * 64) / 256, 256, 0, stream>>>(cbox, sup);
  k_nms_out<<<1, 256, 0, stream>>>(cbox, cscore, ccls, sup, out);
}

// Round 12
// 358.773 us; speedup vs baseline: 1.1634x; 1.1634x over previous
//
#include <hip/hip_runtime.h>
#include <math.h>

#define N_ANCH 134400
#define N_CLS  80
#define TOPK   4096
#define MAX_OUT 300
#define TIECAP 16384

// ---- ws layout (bytes) ----
#define SARR_OFF   0u          // u32[134400] = 537600
#define GHIST_OFF  537600u     // u32[4][256] = 4096
#define STATE_OFF  541696u     // u32 pref(S* prefix), u32 rank
#define CNT_OFF    541704u     // u32 gather counter
#define TIECNT_OFF 541708u     // u32
#define ISTAR_OFF  541712u     // u32
#define TIEBUF_OFF 541728u     // u32[16384] = 65536
#define CANDK_OFF  607264u     // u64[4096] = 32768
#define CBOX_OFF   640032u     // float4[4096] = 65536 (16B aligned)
#define CSCORE_OFF 705568u     // f32[4096]
#define CCLS_OFF   721952u     // i32[4096]
#define SUP_OFF    738336u     // u64[4096*64] = 2097152
#define WS_NEEDED  2835488u
#define MEMSET_OFF 537600u
#define MEMSET_LEN 4112u       // ghist + state + counter + tiecnt

static __device__ __forceinline__ unsigned int ord_f32(float f) {
  unsigned int u = __float_as_uint(f);
  return (u & 0x80000000u) ? ~u : (u | 0x80000000u);
}
static __device__ __forceinline__ float unord_f32(unsigned int o) {
  unsigned int u = (o & 0x80000000u) ? (o ^ 0x80000000u) : ~o;
  return __uint_as_float(u);
}

// K1: per-anchor max class score -> 32-bit order-preserving key
__global__ void k_keys(const float* __restrict__ p, unsigned int* __restrict__ sarr) {
  int i = blockIdx.x * blockDim.x + threadIdx.x;
  if (i >= N_ANCH) return;
  float best = p[4 * N_ANCH + i];
#pragma unroll 4
  for (int c = 1; c < N_CLS; ++c) {
    float v = p[(4 + c) * N_ANCH + i];
    best = fmaxf(best, v);
  }
  float m = (best >= 0.25f) ? best : -INFINITY;
  sarr[i] = ord_f32(m);
}

// Grid-wide 8-bit MSB radix histogram, pass PASS (shift 24-8*PASS).
template <int PASS>
__global__ __launch_bounds__(256) void k_hist(const unsigned int* __restrict__ sarr,
                                              const unsigned int* __restrict__ state,
                                              unsigned int* __restrict__ ghist) {
  __shared__ unsigned int h[256];
  int tid = threadIdx.x;
  h[tid] = 0u;
  __syncthreads();
  int i = blockIdx.x * 256 + tid;   // grid == N_ANCH exactly (525*256)
  unsigned int s = sarr[i];
  if (PASS == 0) {
    atomicAdd(&h[s >> 24], 1u);
  } else {
    const int sh = 24 - 8 * PASS;   // 16, 8, 0
    if ((s >> (sh + 8)) == state[0])
      atomicAdd(&h[(s >> sh) & 255u], 1u);
  }
  __syncthreads();
  if (h[tid]) atomicAdd(&ghist[PASS * 256 + tid], h[tid]);
}

// Scan 256 bins from top, descend one radix level. state = {pref, rank}.
template <int PASS>
__global__ __launch_bounds__(256) void k_scan(const unsigned int* __restrict__ ghist,
                                              unsigned int* __restrict__ state) {
  __shared__ unsigned int h[256];
  int tid = threadIdx.x;
  h[tid] = ghist[PASS * 256 + tid];
  __syncthreads();
  if (tid == 0) {
    unsigned int r    = (PASS == 0) ? (unsigned)TOPK : state[1];
    unsigned int pref = (PASS == 0) ? 0u : state[0];
    unsigned int cum = 0u;
    for (int b = 255; b >= 0; --b) {
      unsigned int c = h[b];
      if (cum + c >= r) { state[0] = (pref << 8) | (unsigned int)b; state[1] = r - cum; break; }
      cum += c;
    }
  }
}

// Collect indices whose score-key equals S* (exact ties at the cut)
__global__ void k_tiecollect(const unsigned int* __restrict__ sarr,
                             const unsigned int* __restrict__ state,
                             unsigned int* __restrict__ tiecnt,
                             unsigned int* __restrict__ tiebuf) {
  int i = blockIdx.x * 256 + threadIdx.x;
  if (sarr[i] == state[0]) {
    unsigned int pos = atomicAdd(tiecnt, 1u);
    if (pos < TIECAP) tiebuf[pos] = (unsigned int)i;
  }
}

// I* = rank-th smallest index among ties (rank = state[1], 1-based).
__global__ __launch_bounds__(256) void k_tiesel(const unsigned int* __restrict__ state,
                                                const unsigned int* __restrict__ tiecnt,
                                                const unsigned int* __restrict__ tiebuf,
                                                unsigned int* __restrict__ Istar) {
  __shared__ unsigned int buf[TIECAP];  // exactly 64KB static LDS
  unsigned int n = *tiecnt; if (n > TIECAP) n = TIECAP;
  unsigned int rf = state[1];
  for (unsigned int t = threadIdx.x; t < n; t += 256) buf[t] = tiebuf[t];
  __syncthreads();
  for (unsigned int t = threadIdx.x; t < n; t += 256) {
    unsigned int v = buf[t], r = 0u;
    for (unsigned int j = 0; j < n; ++j) r += (buf[j] < v) ? 1u : 0u;
    if (r == rf - 1u) *Istar = v;
  }
}

// K3: gather exactly-4096 selected anchors into 64-bit keys (score desc, idx asc)
__global__ void k_gather(const unsigned int* __restrict__ sarr,
                         const unsigned int* __restrict__ state,
                         const unsigned int* __restrict__ Istar,
                         unsigned int* __restrict__ counter,
                         unsigned long long* __restrict__ candk) {
  int i = blockIdx.x * 256 + threadIdx.x;
  unsigned int s = sarr[i];
  unsigned int S = state[0];
  bool take = (s > S) || (s == S && (unsigned int)i <= *Istar);
  if (take) {
    unsigned int pos = atomicAdd(counter, 1u);
    if (pos < TOPK)
      candk[pos] = ((unsigned long long)s << 32) |
                   (unsigned long long)(~(unsigned int)i);
  }
}

// K4: bitonic sort 4096 keys descending in LDS (exact JAX candidate order)
__global__ __launch_bounds__(1024) void k_sort(unsigned long long* __restrict__ candk) {
  __shared__ unsigned long long s[TOPK];
  for (int i = threadIdx.x; i < TOPK; i += 1024) s[i] = candk[i];
  __syncthreads();
  for (int k = 2; k <= TOPK; k <<= 1) {
    for (int j = k >> 1; j > 0; j >>= 1) {
      for (int i = threadIdx.x; i < TOPK; i += 1024) {
        int ixj = i ^ j;
        if (ixj > i) {
          bool up = ((i & k) == 0);
          unsigned long long a = s[i], b = s[ixj];
          bool sw = up ? (a < b) : (a > b);  // descending overall
          if (sw) { s[i] = b; s[ixj] = a; }
        }
      }
      __syncthreads();
    }
  }
  for (int i = threadIdx.x; i < TOPK; i += 1024) candk[i] = s[i];
}

// K5: decode per-candidate box / class / score
__global__ void k_fill(const float* __restrict__ p,
                       const unsigned long long* __restrict__ candk,
                       float4* __restrict__ cbox,
                       float* __restrict__ cscore,
                       int* __restrict__ ccls) {
  int c = blockIdx.x * blockDim.x + threadIdx.x;
  if (c >= TOPK) return;
  unsigned long long k = candk[c];
  float score = unord_f32((unsigned int)(k >> 32));
  int idx = (int)(~(unsigned int)(k & 0xFFFFFFFFull));
  float xc = p[idx];
  float yc = p[N_ANCH + idx];
  float w  = p[2 * N_ANCH + idx];
  float h  = p[3 * N_ANCH + idx];
  float hw = floorf(w * 0.5f), hh = floorf(h * 0.5f);
  cbox[c] = make_float4(xc - hw, yc - hh, xc + hw, yc + hh);
  float best = p[4 * N_ANCH + idx];
  int cls = 0;
  for (int cc = 1; cc < N_CLS; ++cc) {
    float v = p[(4 + cc) * N_ANCH + idx];
    if (v > best) { best = v; cls = cc; }
  }
  cscore[c] = score;
  ccls[c]   = cls;
}

// K6: suppression bitmask matrix (op-for-op reference IoU, j>i baked in)
__global__ void k_iou(const float4* __restrict__ cbox, unsigned long long* __restrict__ sup) {
  int g = blockIdx.x * blockDim.x + threadIdx.x;  // 4096*64 threads
  int row = g >> 6, word = g & 63;
  float4 bi = cbox[row];
  float ai = (bi.z - bi.x) * (bi.w - bi.y);
  unsigned long long m = 0ull;
  int j0 = word << 6;
  if (j0 + 63 > row) {
    for (int b = 0; b < 64; ++b) {
      int j = j0 + b;
      if (j <= row) continue;
      float4 bj = cbox[j];
      float aj = (bj.z - bj.x) * (bj.w - bj.y);
      float ltx = fmaxf(bi.x, bj.x), lty = fmaxf(bi.y, bj.y);
      float rbx = fminf(bi.z, bj.z), rby = fminf(bi.w, bj.w);
      float ww = fmaxf(rbx - ltx, 0.0f), hh = fmaxf(rby - lty, 0.0f);
      float inter = ww * hh;
      float uni = ai + aj - inter;
      float iou = inter / (uni + 1e-9f);
      if (iou > 0.5f) m |= (1ull << b);
    }
  }
  sup[g] = m;
}

// K7: greedy NMS. Keep-state in LDS (skeep[64] u64).
// Phase A (wave 0, serial, registers): intra-chunk survivors via the 64x64
// diagonal block; per-kept-row chain = ctz+shfl+AND, no memory on the chain.
// Phase B (ALL 4 waves, parallel): chunk's kept rows from s_list, each wave
// covers every 4th row — independent coalesced reads stay in flight (the R10
// version issued them serially on one wave and ate full latency per row);
// one 64-bit LDS atomicAnd per wave merges the accumulated suppression.
// Early exit at the 300th kept row (later rows unobservable in the output).
__global__ __launch_bounds__(256) void k_nms_out(const float4* __restrict__ cbox,
                                                 const float* __restrict__ cscore,
                                                 const int* __restrict__ ccls,
                                                 const unsigned long long* __restrict__ sup,
                                                 float* __restrict__ out) {
  __shared__ unsigned long long skeep[64];
  __shared__ int s_list[MAX_OUT];
  __shared__ float s_fs[MAX_OUT];
  __shared__ int s_K;
  __shared__ int s_n0;
  __shared__ int s_cnt;
  int tid = threadIdx.x;
  int lane = tid & 63, wave = tid >> 6;

  // ballot init: word (r*4 + wave) = ballot over coalesced cscore reads
  for (int r = 0; r < 16; ++r) {
    float sc = cscore[r * 256 + tid];
    unsigned long long m = __ballot(sc >= 0.25f);  // isfinite(masked) == passed threshold
    if (lane == 0) skeep[r * 4 + wave] = m;
  }
  if (tid == 0) { s_K = 0; s_n0 = 0; s_cnt = 0; }
  __syncthreads();

  for (int chunk = 0; chunk < 64; ++chunk) {
    unsigned long long cur0 = skeep[chunk];  // uniform; prior Phase B complete
    if (cur0 == 0ull) continue;              // uniform branch, skips barriers
    if (wave == 0) {
      // diagonal 64x64 block: lane l = row (chunk*64+l), word `chunk`
      unsigned long long diag = sup[(chunk * 64 + lane) * 64 + chunk];
      unsigned long long cur = cur0;
      int n = s_K;                           // only wave 0 writes s_K; safe
      if (lane == 0) s_n0 = n;
      while (cur) {
        int b = __builtin_ctzll(cur);        // row chunk*64+b is KEPT (final)
        if (lane == 0) s_list[n] = chunk * 64 + b;
        n++;
        if (n == MAX_OUT) break;
        unsigned long long mb = __shfl(diag, b);  // only j>b bits set
        cur &= ~mb;
        cur = (b == 63) ? 0ull : (cur & (~0ull << (b + 1)));
      }
      if (lane == 0) s_K = n;
    }
    __syncthreads();                         // A-barrier: s_list/s_K/s_n0 visible
    int n0 = s_n0, n1 = s_K;
    if (n1 >= MAX_OUT) break;                // uniform; skip Phase B (unobservable)
    // Phase B: all waves, independent pipelined reads over the kept-row list
    unsigned long long acc = 0ull;
    for (int k = n0 + wave; k < n1; k += 4)
      acc |= sup[(unsigned)s_list[k] * 64 + lane];
    if (acc) atomicAnd(&skeep[lane], ~acc);  // row's own bit never set (j>i only)
    __syncthreads();                         // B-barrier: skeep ready for next chunk
  }
  __syncthreads();

  int K = s_K;
  for (int r = tid; r < MAX_OUT; r += 256)
    s_fs[r] = (r < K) ? cscore[s_list[r]] : 0.0f;
  __syncthreads();

  float slast = s_fs[MAX_OUT - 1], sprev = s_fs[MAX_OUT - 2];
  bool tie = fabsf(slast - sprev) < 1e-6f;
  int local = 0;
  for (int r = tid; r < MAX_OUT; r += 256) {
    float fs = s_fs[r];
    float factor = tie ? ((fs - slast > 1e-5f) ? 1.0f : 0.0f) : 1.0f;
    float so = fs * factor;
    out[4 * MAX_OUT + r] = so;          // scores at [1200, 1500)
    if (so > 1e-5f) local++;
    if (r < K) {
      int c = s_list[r];
      float4 b = cbox[c];
      out[4 * r + 0] = b.x / 640.0f;    // boxes at [0, 1200)
      out[4 * r + 1] = b.y / 640.0f;
      out[4 * r + 2] = b.z / 640.0f;
      out[4 * r + 3] = b.w / 640.0f;
      out[5 * MAX_OUT + r] = (float)ccls[c];  // classes at [1500, 1800)
    } else {
      out[4 * r + 0] = 0.0f; out[4 * r + 1] = 0.0f;
      out[4 * r + 2] = 0.0f; out[4 * r + 3] = 0.0f;
      out[5 * MAX_OUT + r] = 0.0f;
    }
  }
  if (local) atomicAdd(&s_cnt, local);
  __syncthreads();
  if (tid == 0) out[6 * MAX_OUT] = (float)s_cnt;  // count at 1800
}

extern "C" void kernel_launch(void* const* d_in, const int* in_sizes, int n_in,
                              void* d_out, int out_size, void* d_ws, size_t ws_size,
                              hipStream_t stream) {
  const float* p = (const float*)d_in[0];
  float* out = (float*)d_out;
  char* ws = (char*)d_ws;

  if (ws_size < (size_t)WS_NEEDED) return;

  unsigned int* sarr   = (unsigned int*)(ws + SARR_OFF);
  unsigned int* ghist  = (unsigned int*)(ws + GHIST_OFF);
  unsigned int* state  = (unsigned int*)(ws + STATE_OFF);
  unsigned int* counter= (unsigned int*)(ws + CNT_OFF);
  unsigned int* tiecnt = (unsigned int*)(ws + TIECNT_OFF);
  unsigned int* Istar  = (unsigned int*)(ws + ISTAR_OFF);
  unsigned int* tiebuf = (unsigned int*)(ws + TIEBUF_OFF);
  unsigned long long* candk = (unsigned long long*)(ws + CANDK_OFF);
  float4* cbox              = (float4*)(ws + CBOX_OFF);
  float* cscore             = (float*)(ws + CSCORE_OFF);
  int* ccls                 = (int*)(ws + CCLS_OFF);
  unsigned long long* sup   = (unsigned long long*)(ws + SUP_OFF);

  const int NB = N_ANCH / 256;  // 525, exact

  hipMemsetAsync(ws + MEMSET_OFF, 0, MEMSET_LEN, stream);
  k_keys<<<NB, 256, 0, stream>>>(p, sarr);
  k_hist<0><<<NB, 256, 0, stream>>>(sarr, state, ghist);
  k_scan<0><<<1, 256, 0, stream>>>(ghist, state);
  k_hist<1><<<NB, 256, 0, stream>>>(sarr, state, ghist);
  k_scan<1><<<1, 256, 0, stream>>>(ghist, state);
  k_hist<2><<<NB, 256, 0, stream>>>(sarr, state, ghist);
  k_scan<2><<<1, 256, 0, stream>>>(ghist, state);
  k_hist<3><<<NB, 256, 0, stream>>>(sarr, state, ghist);
  k_scan<3><<<1, 256, 0, stream>>>(ghist, state);
  k_tiecollect<<<NB, 256, 0, stream>>>(sarr, state, tiecnt, tiebuf);
  k_tiesel<<<1, 256, 0, stream>>>(state, tiecnt, tiebuf, Istar);
  k_gather<<<NB, 256, 0, stream>>>(sarr, state, Istar, counter, candk);
  k_sort<<<1, 1024, 0, stream>>>(candk);
  k_fill<<<TOPK / 256, 256, 0, stream>>>(p, candk, cbox, cscore, ccls);
  k_iou<<<(TOPK * 64) / 256, 256, 0, stream>>>(cbox, sup);
  k_nms_out<<<1, 256, 0, stream>>>(cbox, cscore, ccls, sup, out);
}

// Round 13
// 310.165 us; speedup vs baseline: 1.3458x; 1.1567x over previous
//
#include <hip/hip_runtime.h>
#include <math.h>

#define N_ANCH 134400
#define N_CLS  80
#define TOPK   4096
#define MAX_OUT 300
#define TIECAP 16384

// ---- ws layout (bytes) ----
#define SARR_OFF   0u          // u32[134400] = 537600
#define GHIST_OFF  537600u     // u32[4][256] = 4096
#define STATE_OFF  541696u     // u32 pref, u32 rank
#define CNT_OFF    541704u     // u32 gather counter
#define TIECNT_OFF 541708u     // u32
#define CLS8_OFF   541712u     // u8[134400] = 134400
#define TIEBUF_OFF 676112u     // u32[16384] = 65536
#define CANDK_OFF  741648u     // u64[4096] = 32768 (8-aligned)
#define CBOX_OFF   774416u     // float4[4096] = 65536 (16-aligned)
#define CSCORE_OFF 839952u     // f32[4096]
#define CCLS_OFF   856336u     // i32[4096]
#define SUP_OFF    872720u     // u64[4096*64] = 2097152
#define WS_NEEDED  2969872u
#define MEMSET_OFF 537600u
#define MEMSET_LEN 4112u       // ghist + state + counter + tiecnt

static __device__ __forceinline__ unsigned int ord_f32(float f) {
  unsigned int u = __float_as_uint(f);
  return (u & 0x80000000u) ? ~u : (u | 0x80000000u);
}
static __device__ __forceinline__ float unord_f32(unsigned int o) {
  unsigned int u = (o & 0x80000000u) ? (o ^ 0x80000000u) : ~o;
  return __uint_as_float(u);
}

// K1: per-anchor max+argmax over 80 classes -> key, class byte, AND pass-0
// radix histogram (merged hist<0>). argmax tie -> lowest class (v > best).
__global__ __launch_bounds__(256) void k_keys(const float* __restrict__ p,
                                              unsigned int* __restrict__ sarr,
                                              unsigned char* __restrict__ cls8,
                                              unsigned int* __restrict__ ghist) {
  __shared__ unsigned int h[256];
  int tid = threadIdx.x;
  h[tid] = 0u;
  __syncthreads();
  int i = blockIdx.x * 256 + tid;
  float best = p[4 * N_ANCH + i];
  int cls = 0;
  for (int c = 1; c < N_CLS; ++c) {
    float v = p[(4 + c) * N_ANCH + i];
    if (v > best) { best = v; cls = c; }
  }
  float m = (best >= 0.25f) ? best : -INFINITY;
  unsigned int s = ord_f32(m);
  sarr[i] = s;
  cls8[i] = (unsigned char)cls;
  atomicAdd(&h[s >> 24], 1u);
  __syncthreads();
  if (h[tid]) atomicAdd(&ghist[tid], h[tid]);  // pass-0 bins at ghist[0..256)
}

// Grid-wide 8-bit MSB radix histogram, passes 1..3
template <int PASS>
__global__ __launch_bounds__(256) void k_hist(const unsigned int* __restrict__ sarr,
                                              const unsigned int* __restrict__ state,
                                              unsigned int* __restrict__ ghist) {
  __shared__ unsigned int h[256];
  int tid = threadIdx.x;
  h[tid] = 0u;
  __syncthreads();
  int i = blockIdx.x * 256 + tid;   // grid == N_ANCH exactly (525*256)
  unsigned int s = sarr[i];
  const int sh = 24 - 8 * PASS;     // 16, 8, 0
  if ((s >> (sh + 8)) == state[0])
    atomicAdd(&h[(s >> sh) & 255u], 1u);
  __syncthreads();
  if (h[tid]) atomicAdd(&ghist[PASS * 256 + tid], h[tid]);
}

// Scan 256 bins from top, descend one radix level. state = {pref, rank}.
template <int PASS>
__global__ __launch_bounds__(256) void k_scan(const unsigned int* __restrict__ ghist,
                                              unsigned int* __restrict__ state) {
  __shared__ unsigned int h[256];
  int tid = threadIdx.x;
  h[tid] = ghist[PASS * 256 + tid];
  __syncthreads();
  if (tid == 0) {
    unsigned int r    = (PASS == 0) ? (unsigned)TOPK : state[1];
    unsigned int pref = (PASS == 0) ? 0u : state[0];
    unsigned int cum = 0u;
    for (int b = 255; b >= 0; --b) {
      unsigned int c = h[b];
      if (cum + c >= r) { state[0] = (pref << 8) | (unsigned int)b; state[1] = r - cum; break; }
      cum += c;
    }
  }
}

// K3a: strict-greater anchors -> candk (unordered); exact-S* ties -> tiebuf
__global__ void k_gathertie(const unsigned int* __restrict__ sarr,
                            const unsigned int* __restrict__ state,
                            unsigned int* __restrict__ counter,
                            unsigned int* __restrict__ tiecnt,
                            unsigned int* __restrict__ tiebuf,
                            unsigned long long* __restrict__ candk) {
  int i = blockIdx.x * 256 + threadIdx.x;
  unsigned int s = sarr[i];
  unsigned int S = state[0];
  if (s > S) {
    unsigned int pos = atomicAdd(counter, 1u);
    if (pos < TOPK)
      candk[pos] = ((unsigned long long)s << 32) |
                   (unsigned long long)(~(unsigned int)i);
  } else if (s == S) {
    unsigned int tp = atomicAdd(tiecnt, 1u);
    if (tp < TIECAP) tiebuf[tp] = (unsigned int)i;
  }
}

// K3b: append the rf lowest-index ties at candk[cnt0 + r], r = index-rank.
// cnt0 + rf == 4096 exactly (radix invariant); indices unique.
__global__ __launch_bounds__(256) void k_tieappend(const unsigned int* __restrict__ state,
                                                   const unsigned int* __restrict__ counter,
                                                   const unsigned int* __restrict__ tiecnt,
                                                   const unsigned int* __restrict__ tiebuf,
                                                   unsigned long long* __restrict__ candk) {
  __shared__ unsigned int buf[TIECAP];  // 64KB static LDS
  unsigned int n = *tiecnt; if (n > TIECAP) n = TIECAP;
  unsigned int rf = state[1];
  unsigned int cnt0 = *counter;
  unsigned long long Shi = ((unsigned long long)state[0]) << 32;
  for (unsigned int t = threadIdx.x; t < n; t += 256) buf[t] = tiebuf[t];
  __syncthreads();
  for (unsigned int t = threadIdx.x; t < n; t += 256) {
    unsigned int v = buf[t], r = 0u;
    for (unsigned int j = 0; j < n; ++j) r += (buf[j] < v) ? 1u : 0u;
    if (r < rf) candk[cnt0 + r] = Shi | (unsigned long long)(~v);
  }
}

// K4: bitonic sort 4096 keys descending in LDS (exact JAX candidate order)
__global__ __launch_bounds__(1024) void k_sort(unsigned long long* __restrict__ candk) {
  __shared__ unsigned long long s[TOPK];
  for (int i = threadIdx.x; i < TOPK; i += 1024) s[i] = candk[i];
  __syncthreads();
  for (int k = 2; k <= TOPK; k <<= 1) {
    for (int j = k >> 1; j > 0; j >>= 1) {
      for (int i = threadIdx.x; i < TOPK; i += 1024) {
        int ixj = i ^ j;
        if (ixj > i) {
          bool up = ((i & k) == 0);
          unsigned long long a = s[i], b = s[ixj];
          bool sw = up ? (a < b) : (a > b);  // descending overall
          if (sw) { s[i] = b; s[ixj] = a; }
        }
      }
      __syncthreads();
    }
  }
  for (int i = threadIdx.x; i < TOPK; i += 1024) candk[i] = s[i];
}

// K5: decode per-candidate box / class / score (class from cls8 — 5 gathers,
// not 84)
__global__ void k_fill(const float* __restrict__ p,
                       const unsigned char* __restrict__ cls8,
                       const unsigned long long* __restrict__ candk,
                       float4* __restrict__ cbox,
                       float* __restrict__ cscore,
                       int* __restrict__ ccls) {
  int c = blockIdx.x * blockDim.x + threadIdx.x;
  if (c >= TOPK) return;
  unsigned long long k = candk[c];
  float score = unord_f32((unsigned int)(k >> 32));
  int idx = (int)(~(unsigned int)(k & 0xFFFFFFFFull));
  float xc = p[idx];
  float yc = p[N_ANCH + idx];
  float w  = p[2 * N_ANCH + idx];
  float h  = p[3 * N_ANCH + idx];
  float hw = floorf(w * 0.5f), hh = floorf(h * 0.5f);
  cbox[c] = make_float4(xc - hw, yc - hh, xc + hw, yc + hh);
  cscore[c] = score;
  ccls[c]   = (int)cls8[idx];
}

// K6: suppression bitmask matrix (op-for-op reference IoU, j>i baked in)
__global__ void k_iou(const float4* __restrict__ cbox, unsigned long long* __restrict__ sup) {
  int g = blockIdx.x * blockDim.x + threadIdx.x;  // 4096*64 threads
  int row = g >> 6, word = g & 63;
  float4 bi = cbox[row];
  float ai = (bi.z - bi.x) * (bi.w - bi.y);
  unsigned long long m = 0ull;
  int j0 = word << 6;
  if (j0 + 63 > row) {
    for (int b = 0; b < 64; ++b) {
      int j = j0 + b;
      if (j <= row) continue;
      float4 bj = cbox[j];
      float aj = (bj.z - bj.x) * (bj.w - bj.y);
      float ltx = fmaxf(bi.x, bj.x), lty = fmaxf(bi.y, bj.y);
      float rbx = fminf(bi.z, bj.z), rby = fminf(bi.w, bj.w);
      float ww = fmaxf(rbx - ltx, 0.0f), hh = fmaxf(rby - lty, 0.0f);
      float inter = ww * hh;
      float uni = ai + aj - inter;
      float iou = inter / (uni + 1e-9f);
      if (iou > 0.5f) m |= (1ull << b);
    }
  }
  sup[g] = m;
}

// K7: greedy NMS. Per chunk: ALL waves issue their 16 row-loads FIRST
// (rowv[16], static indices -> registers), so the global-load latency hides
// under wave 0's Phase A serial scan (diag shfl chain). After the A-barrier,
// each wave ORs its rows masked by the chunk kept-bitmask (branchless) and
// merges via one LDS atomicAnd. No dependent loads on the critical path.
// Early exit at the 300th kept row (later rows unobservable in the output).
__global__ __launch_bounds__(256) void k_nms_out(const float4* __restrict__ cbox,
                                                 const float* __restrict__ cscore,
                                                 const int* __restrict__ ccls,
                                                 const unsigned long long* __restrict__ sup,
                                                 float* __restrict__ out) {
  __shared__ unsigned long long skeep[64];
  __shared__ unsigned long long s_keptl;
  __shared__ int s_list[MAX_OUT];
  __shared__ float s_fs[MAX_OUT];
  __shared__ int s_K;
  __shared__ int s_cnt;
  int tid = threadIdx.x;
  int lane = tid & 63, wave = tid >> 6;

  // ballot init: word (r*4 + wave) = ballot over coalesced cscore reads
  for (int r = 0; r < 16; ++r) {
    float sc = cscore[r * 256 + tid];
    unsigned long long m = __ballot(sc >= 0.25f);  // isfinite(masked) == passed threshold
    if (lane == 0) skeep[r * 4 + wave] = m;
  }
  if (tid == 0) { s_K = 0; s_cnt = 0; }
  __syncthreads();

  for (int chunk = 0; chunk < 64; ++chunk) {
    unsigned long long cur0 = skeep[chunk];  // uniform; prior Phase B complete
    if (cur0 == 0ull) continue;              // uniform branch, skips barriers
    // issue this chunk's 64 row-loads across all 4 waves (latency hides
    // under Phase A); static indexing keeps rowv in registers
    unsigned long long rowv[16];
#pragma unroll
    for (int t = 0; t < 16; ++t)
      rowv[t] = sup[(unsigned)(chunk * 64 + wave * 16 + t) * 64 + lane];
    if (wave == 0) {
      // diagonal 64x64 block: lane l = row (chunk*64+l), word `chunk`
      unsigned long long diag = sup[(chunk * 64 + lane) * 64 + chunk];
      unsigned long long cur = cur0;
      unsigned long long keptl = 0ull;
      int n = s_K;
      while (cur) {
        int b = __builtin_ctzll(cur);        // row chunk*64+b is KEPT (final)
        if (lane == 0) s_list[n] = chunk * 64 + b;
        n++;
        keptl |= (1ull << b);
        if (n == MAX_OUT) break;
        unsigned long long mb = __shfl(diag, b);  // only j>b bits set
        cur &= ~mb;
        cur = (b == 63) ? 0ull : (cur & (~0ull << (b + 1)));
      }
      if (lane == 0) { s_K = n; s_keptl = keptl; }
    }
    __syncthreads();                         // A-barrier: s_K/s_keptl/s_list visible
    if (s_K >= MAX_OUT) break;               // uniform; Phase B unobservable
    unsigned long long keptl = s_keptl;
    unsigned long long acc = 0ull;
#pragma unroll
    for (int t = 0; t < 16; ++t) {
      unsigned long long sel = 0ull - ((keptl >> (wave * 16 + t)) & 1ull);
      acc |= rowv[t] & sel;
    }
    if (acc) atomicAnd(&skeep[lane], ~acc);  // row's own bit never set (j>i only)
    __syncthreads();                         // B-barrier: skeep ready for next chunk
  }
  __syncthreads();

  int K = s_K;
  for (int r = tid; r < MAX_OUT; r += 256)
    s_fs[r] = (r < K) ? cscore[s_list[r]] : 0.0f;
  __syncthreads();

  float slast = s_fs[MAX_OUT - 1], sprev = s_fs[MAX_OUT - 2];
  bool tie = fabsf(slast - sprev) < 1e-6f;
  int local = 0;
  for (int r = tid; r < MAX_OUT; r += 256) {
    float fs = s_fs[r];
    float factor = tie ? ((fs - slast > 1e-5f) ? 1.0f : 0.0f) : 1.0f;
    float so = fs * factor;
    out[4 * MAX_OUT + r] = so;          // scores at [1200, 1500)
    if (so > 1e-5f) local++;
    if (r < K) {
      int c = s_list[r];
      float4 b = cbox[c];
      out[4 * r + 0] = b.x / 640.0f;    // boxes at [0, 1200)
      out[4 * r + 1] = b.y / 640.0f;
      out[4 * r + 2] = b.z / 640.0f;
      out[4 * r + 3] = b.w / 640.0f;
      out[5 * MAX_OUT + r] = (float)ccls[c];  // classes at [1500, 1800)
    } else {
      out[4 * r + 0] = 0.0f; out[4 * r + 1] = 0.0f;
      out[4 * r + 2] = 0.0f; out[4 * r + 3] = 0.0f;
      out[5 * MAX_OUT + r] = 0.0f;
    }
  }
  if (local) atomicAdd(&s_cnt, local);
  __syncthreads();
  if (tid == 0) out[6 * MAX_OUT] = (float)s_cnt;  // count at 1800
}

extern "C" void kernel_launch(void* const* d_in, const int* in_sizes, int n_in,
                              void* d_out, int out_size, void* d_ws, size_t ws_size,
                              hipStream_t stream) {
  const float* p = (const float*)d_in[0];
  float* out = (float*)d_out;
  char* ws = (char*)d_ws;

  if (ws_size < (size_t)WS_NEEDED) return;

  unsigned int* sarr    = (unsigned int*)(ws + SARR_OFF);
  unsigned int* ghist   = (unsigned int*)(ws + GHIST_OFF);
  unsigned int* state   = (unsigned int*)(ws + STATE_OFF);
  unsigned int* counter = (unsigned int*)(ws + CNT_OFF);
  unsigned int* tiecnt  = (unsigned int*)(ws + TIECNT_OFF);
  unsigned char* cls8   = (unsigned char*)(ws + CLS8_OFF);
  unsigned int* tiebuf  = (unsigned int*)(ws + TIEBUF_OFF);
  unsigned long long* candk = (unsigned long long*)(ws + CANDK_OFF);
  float4* cbox              = (float4*)(ws + CBOX_OFF);
  float* cscore             = (float*)(ws + CSCORE_OFF);
  int* ccls                 = (int*)(ws + CCLS_OFF);
  unsigned long long* sup   = (unsigned long long*)(ws + SUP_OFF);

  const int NB = N_ANCH / 256;  // 525, exact

  hipMemsetAsync(ws + MEMSET_OFF, 0, MEMSET_LEN, stream);
  k_keys<<<NB, 256, 0, stream>>>(p, sarr, cls8, ghist);  // merged hist<0>
  k_scan<0><<<1, 256, 0, stream>>>(ghist, state);
  k_hist<1><<<NB, 256, 0, stream>>>(sarr, state, ghist);
  k_scan<1><<<1, 256, 0, stream>>>(ghist, state);
  k_hist<2><<<NB, 256, 0, stream>>>(sarr, state, ghist);
  k_scan<2><<<1, 256, 0, stream>>>(ghist, state);
  k_hist<3><<<NB, 256, 0, stream>>>(sarr, state, ghist);
  k_scan<3><<<1, 256, 0, stream>>>(ghist, state);
  k_gathertie<<<NB, 256, 0, stream>>>(sarr, state, counter, tiecnt, tiebuf, candk);
  k_tieappend<<<1, 256, 0, stream>>>(state, counter, tiecnt, tiebuf, candk);
  k_sort<<<1, 1024, 0, stream>>>(candk);
  k_fill<<<TOPK / 256, 256, 0, stream>>>(p, cls8, candk, cbox, cscore, ccls);
  k_iou<<<(TOPK * 64) / 256, 256, 0, stream>>>(cbox, sup);
  k_nms_out<<<1, 256, 0, stream>>>(cbox, cscore, ccls, sup, out);
}

// Round 14
// 302.831 us; speedup vs baseline: 1.3784x; 1.0242x over previous
//
#include <hip/hip_runtime.h>
#include <math.h>

#define N_ANCH 134400
#define N_CLS  80
#define TOPK   4096
#define MAX_OUT 300
#define TIECAP 16384

// ---- ws layout (bytes) ----
#define SARR_OFF   0u          // u32[134400] = 537600
#define GHIST_OFF  537600u     // u32[4][256] = 4096
#define STATE_OFF  541696u     // u32 pref, u32 rank
#define CNT_OFF    541704u     // u32 gather counter
#define TIECNT_OFF 541708u     // u32
#define CLS8_OFF   541712u     // u8[134400] = 134400
#define TIEBUF_OFF 676112u     // u32[16384] = 65536
#define CANDK_OFF  741648u     // u64[4096] = 32768 (8-aligned)
#define CBOX_OFF   774416u     // float4[4096] = 65536 (16-aligned)
#define CSCORE_OFF 839952u     // f32[4096]
#define CCLS_OFF   856336u     // i32[4096]
#define SUP_OFF    872720u     // u64[4096*64] = 2097152
#define WS_NEEDED  2969872u
#define MEMSET_OFF 537600u
#define MEMSET_LEN 4112u       // ghist + state + counter + tiecnt

static __device__ __forceinline__ unsigned int ord_f32(float f) {
  unsigned int u = __float_as_uint(f);
  return (u & 0x80000000u) ? ~u : (u | 0x80000000u);
}
static __device__ __forceinline__ float unord_f32(unsigned int o) {
  unsigned int u = (o & 0x80000000u) ? (o ^ 0x80000000u) : ~o;
  return __uint_as_float(u);
}

// K1: per-anchor max+argmax over 80 classes -> key, class byte, AND pass-0
// radix histogram (merged hist<0>). argmax tie -> lowest class (v > best).
__global__ __launch_bounds__(256) void k_keys(const float* __restrict__ p,
                                              unsigned int* __restrict__ sarr,
                                              unsigned char* __restrict__ cls8,
                                              unsigned int* __restrict__ ghist) {
  __shared__ unsigned int h[256];
  int tid = threadIdx.x;
  h[tid] = 0u;
  __syncthreads();
  int i = blockIdx.x * 256 + tid;
  float best = p[4 * N_ANCH + i];
  int cls = 0;
  for (int c = 1; c < N_CLS; ++c) {
    float v = p[(4 + c) * N_ANCH + i];
    if (v > best) { best = v; cls = c; }
  }
  float m = (best >= 0.25f) ? best : -INFINITY;
  unsigned int s = ord_f32(m);
  sarr[i] = s;
  cls8[i] = (unsigned char)cls;
  atomicAdd(&h[s >> 24], 1u);
  __syncthreads();
  if (h[tid]) atomicAdd(&ghist[tid], h[tid]);  // pass-0 bins at ghist[0..256)
}

// Grid-wide 8-bit MSB radix histogram, passes 1..3
template <int PASS>
__global__ __launch_bounds__(256) void k_hist(const unsigned int* __restrict__ sarr,
                                              const unsigned int* __restrict__ state,
                                              unsigned int* __restrict__ ghist) {
  __shared__ unsigned int h[256];
  int tid = threadIdx.x;
  h[tid] = 0u;
  __syncthreads();
  int i = blockIdx.x * 256 + tid;   // grid == N_ANCH exactly (525*256)
  unsigned int s = sarr[i];
  const int sh = 24 - 8 * PASS;     // 16, 8, 0
  if ((s >> (sh + 8)) == state[0])
    atomicAdd(&h[(s >> sh) & 255u], 1u);
  __syncthreads();
  if (h[tid]) atomicAdd(&ghist[PASS * 256 + tid], h[tid]);
}

// Scan 256 bins from top, descend one radix level. state = {pref, rank}.
template <int PASS>
__global__ __launch_bounds__(256) void k_scan(const unsigned int* __restrict__ ghist,
                                              unsigned int* __restrict__ state) {
  __shared__ unsigned int h[256];
  int tid = threadIdx.x;
  h[tid] = ghist[PASS * 256 + tid];
  __syncthreads();
  if (tid == 0) {
    unsigned int r    = (PASS == 0) ? (unsigned)TOPK : state[1];
    unsigned int pref = (PASS == 0) ? 0u : state[0];
    unsigned int cum = 0u;
    for (int b = 255; b >= 0; --b) {
      unsigned int c = h[b];
      if (cum + c >= r) { state[0] = (pref << 8) | (unsigned int)b; state[1] = r - cum; break; }
      cum += c;
    }
  }
}

// K3a: strict-greater anchors -> candk (unordered); exact-S* ties -> tiebuf
__global__ void k_gathertie(const unsigned int* __restrict__ sarr,
                            const unsigned int* __restrict__ state,
                            unsigned int* __restrict__ counter,
                            unsigned int* __restrict__ tiecnt,
                            unsigned int* __restrict__ tiebuf,
                            unsigned long long* __restrict__ candk) {
  int i = blockIdx.x * 256 + threadIdx.x;
  unsigned int s = sarr[i];
  unsigned int S = state[0];
  if (s > S) {
    unsigned int pos = atomicAdd(counter, 1u);
    if (pos < TOPK)
      candk[pos] = ((unsigned long long)s << 32) |
                   (unsigned long long)(~(unsigned int)i);
  } else if (s == S) {
    unsigned int tp = atomicAdd(tiecnt, 1u);
    if (tp < TIECAP) tiebuf[tp] = (unsigned int)i;
  }
}

// K3b: append the rf lowest-index ties at candk[cnt0 + r], r = index-rank.
// cnt0 + rf == 4096 exactly (radix invariant); indices unique.
__global__ __launch_bounds__(256) void k_tieappend(const unsigned int* __restrict__ state,
                                                   const unsigned int* __restrict__ counter,
                                                   const unsigned int* __restrict__ tiecnt,
                                                   const unsigned int* __restrict__ tiebuf,
                                                   unsigned long long* __restrict__ candk) {
  __shared__ unsigned int buf[TIECAP];  // 64KB static LDS
  unsigned int n = *tiecnt; if (n > TIECAP) n = TIECAP;
  unsigned int rf = state[1];
  unsigned int cnt0 = *counter;
  unsigned long long Shi = ((unsigned long long)state[0]) << 32;
  for (unsigned int t = threadIdx.x; t < n; t += 256) buf[t] = tiebuf[t];
  __syncthreads();
  for (unsigned int t = threadIdx.x; t < n; t += 256) {
    unsigned int v = buf[t], r = 0u;
    for (unsigned int j = 0; j < n; ++j) r += (buf[j] < v) ? 1u : 0u;
    if (r < rf) candk[cnt0 + r] = Shi | (unsigned long long)(~v);
  }
}

// K4: rank-by-counting + decode, replaces bitonic sort + fill.
// Keys are UNIQUE (low 32 = ~idx), so rank = #{keys > mine} is a bijection
// onto [0,4096): writing to position `rank` reproduces exactly the
// descending-key order (score desc, idx asc). Each block stages all keys in
// LDS (32KB; reads are wave-broadcast, conflict-free), each thread counts
// its candidate's rank and writes box/score/class directly at that position.
__global__ __launch_bounds__(256) void k_rankfill(const float* __restrict__ p,
                                                  const unsigned char* __restrict__ cls8,
                                                  const unsigned long long* __restrict__ candk,
                                                  float4* __restrict__ cbox,
                                                  float* __restrict__ cscore,
                                                  int* __restrict__ ccls) {
  __shared__ unsigned long long keys[TOPK];  // 32KB
  int tid = threadIdx.x;
  for (int i = tid; i < TOPK; i += 256) keys[i] = candk[i];
  __syncthreads();
  int c = blockIdx.x * 256 + tid;            // grid = 16 blocks exactly
  unsigned long long mine = keys[c];
  int cnt = 0;
#pragma unroll 8
  for (int j = 0; j < TOPK; ++j) cnt += (keys[j] > mine) ? 1 : 0;
  float score = unord_f32((unsigned int)(mine >> 32));
  int idx = (int)(~(unsigned int)(mine & 0xFFFFFFFFull));
  float xc = p[idx];
  float yc = p[N_ANCH + idx];
  float w  = p[2 * N_ANCH + idx];
  float h  = p[3 * N_ANCH + idx];
  float hw = floorf(w * 0.5f), hh = floorf(h * 0.5f);
  cbox[cnt] = make_float4(xc - hw, yc - hh, xc + hw, yc + hh);
  cscore[cnt] = score;
  ccls[cnt]   = (int)cls8[idx];
}

// K6: suppression bitmask matrix (op-for-op reference IoU, j>i baked in)
__global__ void k_iou(const float4* __restrict__ cbox, unsigned long long* __restrict__ sup) {
  int g = blockIdx.x * blockDim.x + threadIdx.x;  // 4096*64 threads
  int row = g >> 6, word = g & 63;
  float4 bi = cbox[row];
  float ai = (bi.z - bi.x) * (bi.w - bi.y);
  unsigned long long m = 0ull;
  int j0 = word << 6;
  if (j0 + 63 > row) {
    for (int b = 0; b < 64; ++b) {
      int j = j0 + b;
      if (j <= row) continue;
      float4 bj = cbox[j];
      float aj = (bj.z - bj.x) * (bj.w - bj.y);
      float ltx = fmaxf(bi.x, bj.x), lty = fmaxf(bi.y, bj.y);
      float rbx = fminf(bi.z, bj.z), rby = fminf(bi.w, bj.w);
      float ww = fmaxf(rbx - ltx, 0.0f), hh = fmaxf(rby - lty, 0.0f);
      float inter = ww * hh;
      float uni = ai + aj - inter;
      float iou = inter / (uni + 1e-9f);
      if (iou > 0.5f) m |= (1ull << b);
    }
  }
  sup[g] = m;
}

// K7: greedy NMS. Per chunk: ALL waves issue their 16 row-loads FIRST
// (rowv[16], static indices -> registers), so the global-load latency hides
// under wave 0's Phase A serial scan (diag shfl chain). After the A-barrier,
// each wave ORs its rows masked by the chunk kept-bitmask (branchless) and
// merges via one LDS atomicAnd. No dependent loads on the critical path.
// Early exit at the 300th kept row (later rows unobservable in the output).
__global__ __launch_bounds__(256) void k_nms_out(const float4* __restrict__ cbox,
                                                 const float* __restrict__ cscore,
                                                 const int* __restrict__ ccls,
                                                 const unsigned long long* __restrict__ sup,
                                                 float* __restrict__ out) {
  __shared__ unsigned long long skeep[64];
  __shared__ unsigned long long s_keptl;
  __shared__ int s_list[MAX_OUT];
  __shared__ float s_fs[MAX_OUT];
  __shared__ int s_K;
  __shared__ int s_cnt;
  int tid = threadIdx.x;
  int lane = tid & 63, wave = tid >> 6;

  // ballot init: word (r*4 + wave) = ballot over coalesced cscore reads
  for (int r = 0; r < 16; ++r) {
    float sc = cscore[r * 256 + tid];
    unsigned long long m = __ballot(sc >= 0.25f);  // isfinite(masked) == passed threshold
    if (lane == 0) skeep[r * 4 + wave] = m;
  }
  if (tid == 0) { s_K = 0; s_cnt = 0; }
  __syncthreads();

  for (int chunk = 0; chunk < 64; ++chunk) {
    unsigned long long cur0 = skeep[chunk];  // uniform; prior Phase B complete
    if (cur0 == 0ull) continue;              // uniform branch, skips barriers
    // issue this chunk's 64 row-loads across all 4 waves (latency hides
    // under Phase A); static indexing keeps rowv in registers
    unsigned long long rowv[16];
#pragma unroll
    for (int t = 0; t < 16; ++t)
      rowv[t] = sup[(unsigned)(chunk * 64 + wave * 16 + t) * 64 + lane];
    if (wave == 0) {
      // diagonal 64x64 block: lane l = row (chunk*64+l), word `chunk`
      unsigned long long diag = sup[(chunk * 64 + lane) * 64 + chunk];
      unsigned long long cur = cur0;
      unsigned long long keptl = 0ull;
      int n = s_K;
      while (cur) {
        int b = __builtin_ctzll(cur);        // row chunk*64+b is KEPT (final)
        if (lane == 0) s_list[n] = chunk * 64 + b;
        n++;
        keptl |= (1ull << b);
        if (n == MAX_OUT) break;
        unsigned long long mb = __shfl(diag, b);  // only j>b bits set
        cur &= ~mb;
        cur = (b == 63) ? 0ull : (cur & (~0ull << (b + 1)));
      }
      if (lane == 0) { s_K = n; s_keptl = keptl; }
    }
    __syncthreads();                         // A-barrier: s_K/s_keptl/s_list visible
    if (s_K >= MAX_OUT) break;               // uniform; Phase B unobservable
    unsigned long long keptl = s_keptl;
    unsigned long long acc = 0ull;
#pragma unroll
    for (int t = 0; t < 16; ++t) {
      unsigned long long sel = 0ull - ((keptl >> (wave * 16 + t)) & 1ull);
      acc |= rowv[t] & sel;
    }
    if (acc) atomicAnd(&skeep[lane], ~acc);  // row's own bit never set (j>i only)
    __syncthreads();                         // B-barrier: skeep ready for next chunk
  }
  __syncthreads();

  int K = s_K;
  for (int r = tid; r < MAX_OUT; r += 256)
    s_fs[r] = (r < K) ? cscore[s_list[r]] : 0.0f;
  __syncthreads();

  float slast = s_fs[MAX_OUT - 1], sprev = s_fs[MAX_OUT - 2];
  bool tie = fabsf(slast - sprev) < 1e-6f;
  int local = 0;
  for (int r = tid; r < MAX_OUT; r += 256) {
    float fs = s_fs[r];
    float factor = tie ? ((fs - slast > 1e-5f) ? 1.0f : 0.0f) : 1.0f;
    float so = fs * factor;
    out[4 * MAX_OUT + r] = so;          // scores at [1200, 1500)
    if (so > 1e-5f) local++;
    if (r < K) {
      int c = s_list[r];
      float4 b = cbox[c];
      out[4 * r + 0] = b.x / 640.0f;    // boxes at [0, 1200)
      out[4 * r + 1] = b.y / 640.0f;
      out[4 * r + 2] = b.z / 640.0f;
      out[4 * r + 3] = b.w / 640.0f;
      out[5 * MAX_OUT + r] = (float)ccls[c];  // classes at [1500, 1800)
    } else {
      out[4 * r + 0] = 0.0f; out[4 * r + 1] = 0.0f;
      out[4 * r + 2] = 0.0f; out[4 * r + 3] = 0.0f;
      out[5 * MAX_OUT + r] = 0.0f;
    }
  }
  if (local) atomicAdd(&s_cnt, local);
  __syncthreads();
  if (tid == 0) out[6 * MAX_OUT] = (float)s_cnt;  // count at 1800
}

extern "C" void kernel_launch(void* const* d_in, const int* in_sizes, int n_in,
                              void* d_out, int out_size, void* d_ws, size_t ws_size,
                              hipStream_t stream) {
  const float* p = (const float*)d_in[0];
  float* out = (float*)d_out;
  char* ws = (char*)d_ws;

  if (ws_size < (size_t)WS_NEEDED) return;

  unsigned int* sarr    = (unsigned int*)(ws + SARR_OFF);
  unsigned int* ghist   = (unsigned int*)(ws + GHIST_OFF);
  unsigned int* state   = (unsigned int*)(ws + STATE_OFF);
  unsigned int* counter = (unsigned int*)(ws + CNT_OFF);
  unsigned int* tiecnt  = (unsigned int*)(ws + TIECNT_OFF);
  unsigned char* cls8   = (unsigned char*)(ws + CLS8_OFF);
  unsigned int* tiebuf  = (unsigned int*)(ws + TIEBUF_OFF);
  unsigned long long* candk = (unsigned long long*)(ws + CANDK_OFF);
  float4* cbox              = (float4*)(ws + CBOX_OFF);
  float* cscore             = (float*)(ws + CSCORE_OFF);
  int* ccls                 = (int*)(ws + CCLS_OFF);
  unsigned long long* sup   = (unsigned long long*)(ws + SUP_OFF);

  const int NB = N_ANCH / 256;  // 525, exact

  hipMemsetAsync(ws + MEMSET_OFF, 0, MEMSET_LEN, stream);
  k_keys<<<NB, 256, 0, stream>>>(p, sarr, cls8, ghist);  // merged hist<0>
  k_scan<0><<<1, 256, 0, stream>>>(ghist, state);
  k_hist<1><<<NB, 256, 0, stream>>>(sarr, state, ghist);
  k_scan<1><<<1, 256, 0, stream>>>(ghist, state);
  k_hist<2><<<NB, 256, 0, stream>>>(sarr, state, ghist);
  k_scan<2><<<1, 256, 0, stream>>>(ghist, state);
  k_hist<3><<<NB, 256, 0, stream>>>(sarr, state, ghist);
  k_scan<3><<<1, 256, 0, stream>>>(ghist, state);
  k_gathertie<<<NB, 256, 0, stream>>>(sarr, state, counter, tiecnt, tiebuf, candk);
  k_tieappend<<<1, 256, 0, stream>>>(state, counter, tiecnt, tiebuf, candk);
  k_rankfill<<<TOPK / 256, 256, 0, stream>>>(p, cls8, candk, cbox, cscore, ccls);
  k_iou<<<(TOPK * 64) / 256, 256, 0, stream>>>(cbox, sup);
  k_nms_out<<<1, 256, 0, stream>>>(cbox, cscore, ccls, sup, out);
}